// Round 2
// baseline (939.220 us; speedup 1.0000x reference)
//
#include <hip/hip_runtime.h>
#include <math.h>

// softmask: [B=16, K=64, H=240, W=320] fp32. Per-slice unbiased variance over
// H*W = 76800, sum the 1024 variances, sqrt -> scalar.
//
// Single fused kernel at FULL parallelism (lesson from R1: 1024 blocks = 16
// waves/CU = half occupancy = 3x slower in the L3-latency-bound regime).
// Grid = 5120 chunk-blocks (5 per slice), identical memory pattern to the
// verified 407us stage-1: 256 thr, 15 float4/thread, full unroll.
// Cross-block combine via f64 atomics + counters (device-scope, G16-safe):
//   chunk partials -> per-slice {S,Q} atomic f64 adds
//   last chunk of slice (per-slice counter) -> var -> global acc atomic add
//   last slice overall (global counter) -> sqrt -> out
// Workspace: SQ[1024] double2 | scnt[1024] uint | acc double | gcnt uint
// = 20492 bytes, zeroed by stream-ordered hipMemsetAsync (capture-safe).

#define HW_ELEMS     76800            // 240*320
#define F4_PER_SLICE (HW_ELEMS / 4)   // 19200
#define CHUNKS       5
#define F4_PER_CHUNK (F4_PER_SLICE / CHUNKS)  // 3840
#define BLOCK        256
#define F4_PER_THR   (F4_PER_CHUNK / BLOCK)   // 15 exactly

__global__ __launch_bounds__(BLOCK) void fused_var_kernel(
    const float* __restrict__ in, float* __restrict__ out,
    double2* __restrict__ SQ, unsigned int* __restrict__ scnt,
    double* __restrict__ acc, unsigned int* __restrict__ gcnt,
    int n_slices) {
    const long long chunk = blockIdx.x;  // slice*CHUNKS + c, contiguous memory
    const float4* __restrict__ p =
        (const float4*)in + chunk * F4_PER_CHUNK + threadIdx.x;

    float s = 0.0f, q = 0.0f;
#pragma unroll
    for (int j = 0; j < F4_PER_THR; ++j) {
        float4 v = p[j * BLOCK];
        float x = v.x - 0.5f, y = v.y - 0.5f, z = v.z - 0.5f, w = v.w - 0.5f;
        s += (x + y) + (z + w);
        q += x * x + y * y + z * z + w * w;
    }

    // wave64 shuffle reduction
    for (int off = 32; off > 0; off >>= 1) {
        s += __shfl_down(s, off, 64);
        q += __shfl_down(q, off, 64);
    }

    __shared__ float ss[BLOCK / 64], qq[BLOCK / 64];
    if ((threadIdx.x & 63) == 0) {
        ss[threadIdx.x >> 6] = s;
        qq[threadIdx.x >> 6] = q;
    }
    __syncthreads();

    if (threadIdx.x == 0) {
        float S = 0.0f, Q = 0.0f;
        for (int w = 0; w < BLOCK / 64; ++w) { S += ss[w]; Q += qq[w]; }

        const int slice = (int)(blockIdx.x) / CHUNKS;
        atomicAdd(&SQ[slice].x, (double)S);
        atomicAdd(&SQ[slice].y, (double)Q);
        __threadfence();  // release: S/Q adds visible before counter bump
        const unsigned int old = atomicAdd(&scnt[slice], 1u);
        if (old == CHUNKS - 1) {      // last chunk of this slice
            __threadfence();          // acquire
            const double Sd = atomicAdd(&SQ[slice].x, 0.0);  // coherent reads
            const double Qd = atomicAdd(&SQ[slice].y, 0.0);
            const double n = (double)HW_ELEMS;
            const double var = (Qd - Sd * Sd / n) / (n - 1.0);

            atomicAdd(acc, var);
            __threadfence();          // release
            const unsigned int g = atomicAdd(gcnt, 1u);
            if (g == (unsigned int)n_slices - 1u) {  // last slice overall
                __threadfence();      // acquire
                const double tot = atomicAdd(acc, 0.0);
                out[0] = (float)sqrt(tot);
            }
        }
    }
}

extern "C" void kernel_launch(void* const* d_in, const int* in_sizes, int n_in,
                              void* d_out, int out_size, void* d_ws, size_t ws_size,
                              hipStream_t stream) {
    const float* softmask = (const float*)d_in[0];
    float* out = (float*)d_out;

    const int n_slices = in_sizes[0] / HW_ELEMS;  // 1024

    // Workspace layout (16B-aligned pieces first)
    double2* SQ = (double2*)d_ws;                                   // 16 KB
    unsigned int* scnt = (unsigned int*)((char*)d_ws + 16384);      // 4 KB
    double* acc = (double*)((char*)d_ws + 20480);                   // 8 B
    unsigned int* gcnt = (unsigned int*)((char*)d_ws + 20488);      // 4 B

    hipMemsetAsync(d_ws, 0, 20492, stream);  // zero partials+counters (capturable)
    fused_var_kernel<<<n_slices * CHUNKS, BLOCK, 0, stream>>>(
        softmask, out, SQ, scnt, acc, gcnt, n_slices);
}

// Round 3
// 408.074 us; speedup vs baseline: 2.3016x; 2.3016x over previous
//
#include <hip/hip_runtime.h>
#include <hip/hip_bf16.h>
#include <math.h>

// softmask: [B=16, K=64, H=240, W=320] fp32. Per-slice unbiased variance over
// H*W = 76800, sum the 1024 variances, sqrt -> scalar.
//
// REVERT to the verified two-kernel structure (R0: 407.06 us). R1/R2 proved
// that fusing via device-scope f64 atomics + __threadfence regresses 12-25x
// on the kernel: the fences lower to L2 writeback/invalidate (sc1), and 5120
// blocks issuing them invalidate the L2/L3-resident input other blocks are
// streaming (R2: 700 us @ 2.7% HBM, VALUBusy 1.2%). A second 1-block launch
// costs ~3 us and keeps both kernels fence-free.
//
// Stage 1: 5 chunks/slice, fp32 accumulation of sum(x-0.5) / sum((x-0.5)^2).
//   Shift-by-0.5 makes the later S^2/n cancellation benign, so no fp64 in the
//   hot loop. 15 float4/thread, compile-time trip count -> full unroll.
// Stage 2: 1 block, 1 thread/slice, combine chunk partials in double,
//   var = (Q - S^2/n)/(n-1), block-reduce, sqrt.

#define HW_ELEMS     76800            // 240*320
#define F4_PER_SLICE (HW_ELEMS / 4)   // 19200
#define CHUNKS       5
#define F4_PER_CHUNK (F4_PER_SLICE / CHUNKS)  // 3840
#define BLOCK        256
#define F4_PER_THR   (F4_PER_CHUNK / BLOCK)   // 15 exactly

__global__ __launch_bounds__(BLOCK) void chunk_partial_kernel(
    const float* __restrict__ in, float2* __restrict__ partials) {
    const long long chunk = blockIdx.x;  // slice*CHUNKS + c, contiguous memory
    const float4* __restrict__ p =
        (const float4*)in + chunk * F4_PER_CHUNK + threadIdx.x;

    float s = 0.0f, q = 0.0f;
#pragma unroll
    for (int j = 0; j < F4_PER_THR; ++j) {
        float4 v = p[j * BLOCK];
        float x = v.x - 0.5f, y = v.y - 0.5f, z = v.z - 0.5f, w = v.w - 0.5f;
        s += (x + y) + (z + w);
        q += x * x + y * y + z * z + w * w;
    }

    // wave64 shuffle reduction
    for (int off = 32; off > 0; off >>= 1) {
        s += __shfl_down(s, off, 64);
        q += __shfl_down(q, off, 64);
    }

    __shared__ float ss[BLOCK / 64], qq[BLOCK / 64];
    if ((threadIdx.x & 63) == 0) {
        ss[threadIdx.x >> 6] = s;
        qq[threadIdx.x >> 6] = q;
    }
    __syncthreads();

    if (threadIdx.x == 0) {
        float S = 0.0f, Q = 0.0f;
        for (int w = 0; w < BLOCK / 64; ++w) { S += ss[w]; Q += qq[w]; }
        partials[chunk] = make_float2(S, Q);
    }
}

// One thread per slice; n_slices <= 1024 assumed (it's exactly 1024 here).
__global__ __launch_bounds__(1024) void finalize_kernel(
    const float2* __restrict__ partials, float* __restrict__ out, int n_slices) {
    double var = 0.0;
    if ((int)threadIdx.x < n_slices) {
        double S = 0.0, Q = 0.0;
        const float2* p = partials + (long long)threadIdx.x * CHUNKS;
        for (int c = 0; c < CHUNKS; ++c) {
            float2 pq = p[c];
            S += (double)pq.x;
            Q += (double)pq.y;
        }
        const double n = (double)HW_ELEMS;
        var = (Q - S * S / n) / (n - 1.0);
    }

    for (int off = 32; off > 0; off >>= 1) var += __shfl_down(var, off, 64);

    __shared__ double sh[1024 / 64];
    if ((threadIdx.x & 63) == 0) sh[threadIdx.x >> 6] = var;
    __syncthreads();

    if (threadIdx.x == 0) {
        double tot = 0.0;
        for (int w = 0; w < 1024 / 64; ++w) tot += sh[w];
        out[0] = (float)sqrt(tot);
    }
}

extern "C" void kernel_launch(void* const* d_in, const int* in_sizes, int n_in,
                              void* d_out, int out_size, void* d_ws, size_t ws_size,
                              hipStream_t stream) {
    const float* softmask = (const float*)d_in[0];
    float* out = (float*)d_out;
    float2* partials = (float2*)d_ws;  // n_slices*CHUNKS float2

    const int n_slices = in_sizes[0] / HW_ELEMS;  // 1024

    chunk_partial_kernel<<<n_slices * CHUNKS, BLOCK, 0, stream>>>(softmask, partials);
    finalize_kernel<<<1, 1024, 0, stream>>>(partials, out, n_slices);
}